// Round 8
// baseline (441.282 us; speedup 1.0000x reference)
//
#include <hip/hip_runtime.h>
#include <math.h>

#define BATCH 4
#define CH 512
#define NTOK 4096
#define NGRP 32
#define CPG 16
#define GN_EPS 1e-6f

typedef __attribute__((ext_vector_type(8))) short short8;
typedef __attribute__((ext_vector_type(4))) short short4v;
typedef __attribute__((ext_vector_type(4))) float floatx4;

__device__ __forceinline__ short f2bf(float f) {
    unsigned u = __float_as_uint(f);
    u += 0x7fffu + ((u >> 16) & 1u);
    return (short)(u >> 16);
}
__device__ __forceinline__ float bf2f(short s) {
    return __uint_as_float(((unsigned)(unsigned short)s) << 16);
}

__device__ __forceinline__ void load_lds16(const void* g, void* l) {
    __builtin_amdgcn_global_load_lds(
        (const __attribute__((address_space(1))) void*)g,
        (__attribute__((address_space(3))) void*)l,
        16, 0, 0);
}

// ---------------------------------------------------------------------------
// GroupNorm stats, partial: grid (4 parts, 128 bg). partials[bg*4+p]=(sum,ssq)
// ---------------------------------------------------------------------------
__global__ __launch_bounds__(256)
void gn_stats_partial(const float* __restrict__ x, float2* __restrict__ partials)
{
    const int part = blockIdx.x;
    const int bg = blockIdx.y;
    const float4* xp = (const float4*)(x + (size_t)bg * CPG * NTOK) + part * 4096;
    float s = 0.f, ss = 0.f;
    for (int i = threadIdx.x; i < 4096; i += 256) {
        float4 v = xp[i];
        s  += v.x + v.y + v.z + v.w;
        ss += v.x * v.x + v.y * v.y + v.z * v.z + v.w * v.w;
    }
    __shared__ float r0[4], r1[4];
    for (int off = 32; off >= 1; off >>= 1) {
        s  += __shfl_down(s, off);
        ss += __shfl_down(ss, off);
    }
    const int lane = threadIdx.x & 63, wave = threadIdx.x >> 6;
    if (lane == 0) { r0[wave] = s; r1[wave] = ss; }
    __syncthreads();
    if (threadIdx.x == 0) {
        float2 o;
        o.x = r0[0] + r0[1] + r0[2] + r0[3];
        o.y = r1[0] + r1[1] + r1[2] + r1[3];
        partials[bg * 4 + part] = o;
    }
}

// ---------------------------------------------------------------------------
// GroupNorm apply + transpose + bf16. x[b][c][n] -> hnT[b][n][c] bf16.
// ---------------------------------------------------------------------------
__global__ __launch_bounds__(256)
void gn_apply_t(const float* __restrict__ x, const float* __restrict__ gamma,
                const float* __restrict__ beta, const float2* __restrict__ partials,
                short* __restrict__ hnT)
{
    const int b = blockIdx.z;
    const int c0 = blockIdx.y * 32;
    const int n0 = blockIdx.x * 32;
    __shared__ short tile[32][33];
    const int t = threadIdx.x;

    const int cl = t >> 3;
    const int nl = (t & 7) * 4;
    const int c = c0 + cl;
    const int bg = b * NGRP + c / CPG;
    float2 p0 = partials[bg * 4 + 0], p1 = partials[bg * 4 + 1];
    float2 p2 = partials[bg * 4 + 2], p3 = partials[bg * 4 + 3];
    const float inv = 1.f / (float)(CPG * NTOK);
    const float mean = (p0.x + p1.x + p2.x + p3.x) * inv;
    const float var = (p0.y + p1.y + p2.y + p3.y) * inv - mean * mean;
    const float rstd = rsqrtf(var + GN_EPS);
    const float ga = gamma[c] * rstd, be = beta[c] - mean * ga;
    const float4 v = *(const float4*)(x + ((size_t)b * CH + c) * NTOK + n0 + nl);
    tile[cl][nl + 0] = f2bf(v.x * ga + be);
    tile[cl][nl + 1] = f2bf(v.y * ga + be);
    tile[cl][nl + 2] = f2bf(v.z * ga + be);
    tile[cl][nl + 3] = f2bf(v.w * ga + be);
    __syncthreads();

    const int nw = t >> 3;
    const int cw = (t & 7) * 4;
    short4v o;
    o.x = tile[cw + 0][nw];
    o.y = tile[cw + 1][nw];
    o.z = tile[cw + 2][nw];
    o.w = tile[cw + 3][nw];
    *(short4v*)(hnT + ((size_t)b * NTOK + n0 + nw) * CH + c0 + cw) = o;
}

// ---------------------------------------------------------------------------
// Weight casts. Grid (256, 4).
// ---------------------------------------------------------------------------
__global__ __launch_bounds__(256)
void cast_weights(const float* q, const float* k, const float* v, const float* p,
                  short* wqk, short* wv, short* wp)
{
    const float* w; short* o;
    switch (blockIdx.y) {
        case 0: w = q; o = wqk; break;
        case 1: w = k; o = wqk + CH * CH; break;
        case 2: w = v; o = wv; break;
        default: w = p; o = wp; break;
    }
    const int i = blockIdx.x * 256 + threadIdx.x;
    const float4 vv = ((const float4*)w)[i];
    short4v s; s.x = f2bf(vv.x); s.y = f2bf(vv.y); s.z = f2bf(vv.z); s.w = f2bf(vv.w);
    ((short4v*)o)[i] = s;
}

__global__ __launch_bounds__(256)
void concat_bias(const float* q_b, const float* k_b, float* qkb)
{
    const int i = blockIdx.x * 256 + threadIdx.x;
    qkb[i] = (i < CH) ? q_b[i] : k_b[i - CH];
}

__global__ __launch_bounds__(256)
void zero_f32(float* __restrict__ p)
{
    p[blockIdx.x * 256 + threadIdx.x] = 0.f;
}

// ---------------------------------------------------------------------------
// bf16 MFMA GEMM (TN): C[m][n] = scale*sum_k A[m][k]*B[n][k] (+bias)(+res)
// MODE: 0 = fp32 out (direct store), 1 = bf16 out, 2 = bf16 exp(out)
// MODE>=1: chunked LDS-staged epilogue (64 rows at a time, coalesced stores).
// RSUM (MODE==2 only): atomicAdd per-row sums of exp into rs[zb*NTOK + row].
// SPLITK: z encodes (split=z>>2, batch=z&3); k-range offset split*K.
// T2 swizzle: linear LDS dest (global_load_lds constraint), XOR-permuted
// global source chunk, same XOR on the ds_read offset (rule #21).
// BK=32 for scores/PV: 17.4 KB LDS -> ~6 blocks/CU. Occupancy/TLP is the
// dominant lever at this problem size (rounds 0/2/3/5/7 evidence) — the
// cross-block overlap covers load-service latency that lockstep 1-block/CU
// pipelines (null: rounds 3,7) cannot.
// ---------------------------------------------------------------------------
template<int BM, int BN, int BK, int WAVES_M, int MODE, int BIAS_M,
         int BIAS_N, int ADD_RES, int SWAP_XY, int SPLITK, int RSUM>
__global__ __launch_bounds__(256)
void mfma_gemm(const short* __restrict__ A, const short* __restrict__ B,
               void* __restrict__ Cv, const float* __restrict__ bias,
               const float* __restrict__ res, float* __restrict__ rs,
               float scale,
               int K, int lda, int ldb, int ldc,
               long sA, long sB, long sC)
{
    constexpr int WAVES_N = 4 / WAVES_M;
    constexpr int WM = BM / WAVES_M;
    constexpr int WN = BN / WAVES_N;
    constexpr int MT = WM / 16;
    constexpr int NT = WN / 16;
    constexpr int KS = BK / 32;
    constexpr int TPR = BK / 8;
    constexpr int RPI = 256 / TPR;
    constexpr int CPITCH = BN + 8;
    constexpr int STAGE = BM * BK + BN * BK;
    constexpr int EPI = (MODE >= 1) ? 64 * CPITCH : 0;
    constexpr int LDSE = STAGE > EPI ? STAGE : EPI;

    __shared__ __align__(16) short lds[LDSE];
    short* As = lds;
    short* Bs = lds + BM * BK;

    const int z = blockIdx.z;
    const int zb = SPLITK ? (z & 3) : z;
    const int koff = SPLITK ? (z >> 2) * K : 0;
    const short* Ap = A + (size_t)zb * sA + koff;
    const short* Bp = B + (size_t)zb * sB + koff;

    const int m0 = (SWAP_XY ? blockIdx.x : blockIdx.y) * BM;
    const int n0 = (SWAP_XY ? blockIdx.y : blockIdx.x) * BN;
    const int t = threadIdx.x;
    const int w = t >> 6, lane = t & 63;
    const int wm = (w % WAVES_M) * WM;
    const int wn = (w / WAVES_M) * WN;
    const int lr = lane & 15, lq = lane >> 4;

    floatx4 acc[MT][NT];
#pragma unroll
    for (int mt = 0; mt < MT; mt++)
#pragma unroll
        for (int nt = 0; nt < NT; nt++)
            acc[mt][nt] = (floatx4){0.f, 0.f, 0.f, 0.f};

    const int rA = t / TPR;
    const int kA = (t % TPR) * 8;
    const int kAs = ((t % TPR) ^ (rA & (TPR - 1))) * 8;
    const int xorv = (lr & (TPR - 1)) * 8;

    for (int k0 = 0; k0 < K; k0 += BK) {
#pragma unroll
        for (int r = 0; r < BM; r += RPI)
            load_lds16(Ap + (size_t)(m0 + r + rA) * lda + k0 + kAs,
                       &As[(r + rA) * BK + kA]);
#pragma unroll
        for (int r = 0; r < BN; r += RPI)
            load_lds16(Bp + (size_t)(n0 + r + rA) * ldb + k0 + kAs,
                       &Bs[(r + rA) * BK + kA]);
        __syncthreads();

#pragma unroll
        for (int ks = 0; ks < KS; ks++) {
            short8 af[MT], bfr[NT];
#pragma unroll
            for (int mt = 0; mt < MT; mt++)
                af[mt] = *(const short8*)&As[(wm + mt * 16 + lr) * BK + ((ks * 32 + lq * 8) ^ xorv)];
#pragma unroll
            for (int nt = 0; nt < NT; nt++)
                bfr[nt] = *(const short8*)&Bs[(wn + nt * 16 + lr) * BK + ((ks * 32 + lq * 8) ^ xorv)];
#pragma unroll
            for (int mt = 0; mt < MT; mt++)
#pragma unroll
                for (int nt = 0; nt < NT; nt++)
                    acc[mt][nt] = __builtin_amdgcn_mfma_f32_16x16x32_bf16(
                        af[mt], bfr[nt], acc[mt][nt], 0, 0, 0);
        }
        __syncthreads();
    }

    // C/D: col = lane&15, row = (lane>>4)*4 + r  [m89-verified]
    const size_t cz = (size_t)z * sC;
    if (MODE >= 1) {
        short* Cs = lds;
        short* Cout2 = (short*)Cv;
        constexpr int VPR = BN / 8;
#pragma unroll
        for (int c = 0; c < BM / 64; c++) {
            if (wm == c * 64) {
#pragma unroll
                for (int mt = 0; mt < MT; mt++) {
#pragma unroll
                    for (int r = 0; r < 4; r++) {
                        const int rowLoc = wm + mt * 16 + lq * 4 + r;
                        const int rowCs = rowLoc - c * 64;
                        const float bm = BIAS_M ? bias[m0 + rowLoc] : 0.f;
                        float s = 0.f;
#pragma unroll
                        for (int nt = 0; nt < NT; nt++) {
                            const int colLoc = wn + nt * 16 + lr;
                            float v = acc[mt][nt][r] * scale + bm;
                            if (BIAS_N) v += bias[n0 + colLoc];
                            if (MODE == 2) v = __expf(v);
                            if (RSUM) s += v;
                            Cs[rowCs * CPITCH + colLoc] = f2bf(v);
                        }
                        if (RSUM) {
                            s += __shfl_xor(s, 1);
                            s += __shfl_xor(s, 2);
                            s += __shfl_xor(s, 4);
                            s += __shfl_xor(s, 8);
                            if (lr == 0)
                                atomicAdd(&rs[(size_t)zb * NTOK + m0 + rowLoc], s);
                        }
                    }
                }
            }
            __syncthreads();
            constexpr int ITER = 64 * VPR / 256;
#pragma unroll
            for (int i = 0; i < ITER; i++) {
                const int idx = i * 256 + t;
                const int row = idx / VPR;
                const int cv = idx % VPR;
                short8 val = *(const short8*)&Cs[row * CPITCH + cv * 8];
                *(short8*)&Cout2[cz + (size_t)(m0 + c * 64 + row) * ldc + n0 + cv * 8] = val;
            }
            if (c + 1 < BM / 64) __syncthreads();
        }
    } else {
#pragma unroll
        for (int mt = 0; mt < MT; mt++) {
#pragma unroll
            for (int r = 0; r < 4; r++) {
                const int row = m0 + wm + mt * 16 + lq * 4 + r;
                const float bm = BIAS_M ? bias[row] : 0.f;
#pragma unroll
                for (int nt = 0; nt < NT; nt++) {
                    const int col = n0 + wn + nt * 16 + lr;
                    float v = acc[mt][nt][r] * scale + bm;
                    if (BIAS_N) v += bias[col];
                    const size_t idx = cz + (size_t)row * ldc + col;
                    if (ADD_RES) v += res[idx];
                    ((float*)Cv)[idx] = v;
                }
            }
        }
    }
}

// ---------------------------------------------------------------------------
// Split-K reduce: O[row][c] = (P0 + P1) / RS[row].
// ---------------------------------------------------------------------------
__global__ __launch_bounds__(256)
void pv_reduce(const short* __restrict__ P0, const short* __restrict__ P1,
               const float* __restrict__ RS, short* __restrict__ O)
{
    const int idx = blockIdx.x * 256 + threadIdx.x;   // short8 units
    const int row = idx >> 6;                         // 64 units per 512-col row
    const float inv = 1.f / RS[row];
    short8 a = ((const short8*)P0)[idx];
    short8 b = ((const short8*)P1)[idx];
    short8 o;
#pragma unroll
    for (int e = 0; e < 8; e++)
        o[e] = f2bf((bf2f(a[e]) + bf2f(b[e])) * inv);
    ((short8*)O)[idx] = o;
}

// ---------------------------------------------------------------------------
// Launch
// ---------------------------------------------------------------------------
extern "C" void kernel_launch(void* const* d_in, const int* in_sizes, int n_in,
                              void* d_out, int out_size, void* d_ws, size_t ws_size,
                              hipStream_t stream)
{
    (void)in_sizes; (void)n_in; (void)out_size; (void)ws_size;
    const float* x      = (const float*)d_in[0];
    const float* norm_w = (const float*)d_in[1];
    const float* norm_b = (const float*)d_in[2];
    const float* q_w    = (const float*)d_in[3];
    const float* q_b    = (const float*)d_in[4];
    const float* k_w    = (const float*)d_in[5];
    const float* k_b    = (const float*)d_in[6];
    const float* v_w    = (const float*)d_in[7];
    const float* v_b    = (const float*)d_in[8];
    const float* p_w    = (const float*)d_in[9];
    const float* p_b    = (const float*)d_in[10];

    const size_t CN2 = (size_t)NTOK * CH;

    short* hnT = (short*)d_ws;                        // [B][N][C]
    short* QK  = hnT + (size_t)BATCH * CN2;           // [B][N][1024]; later PV partials [2][B][N][C]
    short* V   = QK  + (size_t)BATCH * NTOK * 1024;   // [B][C][N]
    short* O   = V   + (size_t)BATCH * CN2;           // [B][N][C]
    short* wqk = O   + (size_t)BATCH * CN2;           // [1024][512]
    short* wv  = wqk + (size_t)1024 * CH;
    short* wp  = wv  + (size_t)CH * CH;
    short* S   = wp  + (size_t)CH * CH;               // E = exp(scores) [B][N][N] bf16
    float* qkb = (float*)(S + (size_t)BATCH * NTOK * NTOK);   // [1024]
    float2* partials = (float2*)(qkb + 1024);                 // [512]
    float* RS = (float*)(partials + 512);                     // [B][N] rowsums

    gn_stats_partial<<<dim3(4, BATCH * NGRP), 256, 0, stream>>>(x, partials);
    cast_weights<<<dim3(256, 4), 256, 0, stream>>>(q_w, k_w, v_w, p_w, wqk, wv, wp);
    concat_bias<<<4, 256, 0, stream>>>(q_b, k_b, qkb);
    zero_f32<<<BATCH * NTOK / 256, 256, 0, stream>>>(RS);
    gn_apply_t<<<dim3(NTOK / 32, CH / 32, BATCH), 256, 0, stream>>>(
        x, norm_w, norm_b, partials, hnT);

    // Fused Q+K conv (128^2, BK=64)
    mfma_gemm<128, 128, 64, 2, 1, 0, 1, 0, 0, 0, 0><<<dim3(1024 / 128, NTOK / 128, BATCH), 256, 0, stream>>>(
        hnT, wqk, QK, qkb, nullptr, nullptr, 1.f, CH, CH, CH, 1024,
        (long)CN2, 0, (long)NTOK * 1024);
    // V conv
    mfma_gemm<128, 128, 64, 2, 1, 1, 0, 0, 0, 0, 0><<<dim3(NTOK / 128, CH / 128, BATCH), 256, 0, stream>>>(
        wv, hnT, V, v_b, nullptr, nullptr, 1.f, CH, CH, CH, NTOK,
        0, (long)CN2, (long)CN2);

    const float scale = 1.0f / sqrtf((float)CH);
    // scores -> E = exp(s*scale) bf16 + fused row sums.
    // 128^2 BK=32 + T2 swizzle: ~6 blocks/CU for cross-block latency hiding.
    mfma_gemm<128, 128, 32, 2, 2, 0, 0, 0, 0, 0, 1><<<dim3(NTOK / 128, NTOK / 128, BATCH), 256, 0, stream>>>(
        QK, QK + CH, S, nullptr, nullptr, RS, scale, CH, 1024, 1024, NTOK,
        (long)NTOK * 1024, (long)NTOK * 1024, (long)NTOK * NTOK);
    // PV split-K=2, 128^2 BK=32, bf16 partials over QK buffer
    mfma_gemm<128, 128, 32, 2, 1, 0, 0, 0, 1, 1, 0><<<dim3(NTOK / 128, CH / 128, 8), 256, 0, stream>>>(
        S, V, QK, nullptr, nullptr, nullptr, 1.f, NTOK / 2, NTOK, NTOK, CH,
        (long)NTOK * NTOK, (long)CN2, (long)CN2);
    // combine partials, divide by rowsum -> O bf16
    pv_reduce<<<(BATCH * NTOK * CH / 8) / 256, 256, 0, stream>>>(
        QK, QK + (size_t)BATCH * CN2, RS, O);

    // proj + bias + residual -> out fp32 [b][c][n]
    mfma_gemm<128, 128, 64, 2, 0, 1, 0, 1, 0, 0, 0><<<dim3(NTOK / 128, CH / 128, BATCH), 256, 0, stream>>>(
        wp, O, d_out, p_b, x, nullptr, 1.f, CH, CH, CH, NTOK,
        0, (long)CN2, (long)CN2);
}

// Round 9
// 373.041 us; speedup vs baseline: 1.1829x; 1.1829x over previous
//
#include <hip/hip_runtime.h>
#include <math.h>

#define BATCH 4
#define CH 512
#define NTOK 4096
#define NGRP 32
#define CPG 16
#define GN_EPS 1e-6f

typedef __attribute__((ext_vector_type(8))) short short8;
typedef __attribute__((ext_vector_type(4))) short short4v;
typedef __attribute__((ext_vector_type(4))) float floatx4;

__device__ __forceinline__ short f2bf(float f) {
    unsigned u = __float_as_uint(f);
    u += 0x7fffu + ((u >> 16) & 1u);
    return (short)(u >> 16);
}
__device__ __forceinline__ float bf2f(short s) {
    return __uint_as_float(((unsigned)(unsigned short)s) << 16);
}

__device__ __forceinline__ void load_lds16(const void* g, void* l) {
    __builtin_amdgcn_global_load_lds(
        (const __attribute__((address_space(1))) void*)g,
        (__attribute__((address_space(3))) void*)l,
        16, 0, 0);
}

// ---------------------------------------------------------------------------
// GroupNorm stats, partial: grid (4 parts, 128 bg). partials[bg*4+p]=(sum,ssq)
// ---------------------------------------------------------------------------
__global__ __launch_bounds__(256)
void gn_stats_partial(const float* __restrict__ x, float2* __restrict__ partials)
{
    const int part = blockIdx.x;
    const int bg = blockIdx.y;
    const float4* xp = (const float4*)(x + (size_t)bg * CPG * NTOK) + part * 4096;
    float s = 0.f, ss = 0.f;
    for (int i = threadIdx.x; i < 4096; i += 256) {
        float4 v = xp[i];
        s  += v.x + v.y + v.z + v.w;
        ss += v.x * v.x + v.y * v.y + v.z * v.z + v.w * v.w;
    }
    __shared__ float r0[4], r1[4];
    for (int off = 32; off >= 1; off >>= 1) {
        s  += __shfl_down(s, off);
        ss += __shfl_down(ss, off);
    }
    const int lane = threadIdx.x & 63, wave = threadIdx.x >> 6;
    if (lane == 0) { r0[wave] = s; r1[wave] = ss; }
    __syncthreads();
    if (threadIdx.x == 0) {
        float2 o;
        o.x = r0[0] + r0[1] + r0[2] + r0[3];
        o.y = r1[0] + r1[1] + r1[2] + r1[3];
        partials[bg * 4 + part] = o;
    }
}

// ---------------------------------------------------------------------------
// GroupNorm apply + transpose + bf16. x[b][c][n] -> hnT[b][n][c] bf16.
// ---------------------------------------------------------------------------
__global__ __launch_bounds__(256)
void gn_apply_t(const float* __restrict__ x, const float* __restrict__ gamma,
                const float* __restrict__ beta, const float2* __restrict__ partials,
                short* __restrict__ hnT)
{
    const int b = blockIdx.z;
    const int c0 = blockIdx.y * 32;
    const int n0 = blockIdx.x * 32;
    __shared__ short tile[32][33];
    const int t = threadIdx.x;

    const int cl = t >> 3;
    const int nl = (t & 7) * 4;
    const int c = c0 + cl;
    const int bg = b * NGRP + c / CPG;
    float2 p0 = partials[bg * 4 + 0], p1 = partials[bg * 4 + 1];
    float2 p2 = partials[bg * 4 + 2], p3 = partials[bg * 4 + 3];
    const float inv = 1.f / (float)(CPG * NTOK);
    const float mean = (p0.x + p1.x + p2.x + p3.x) * inv;
    const float var = (p0.y + p1.y + p2.y + p3.y) * inv - mean * mean;
    const float rstd = rsqrtf(var + GN_EPS);
    const float ga = gamma[c] * rstd, be = beta[c] - mean * ga;
    const float4 v = *(const float4*)(x + ((size_t)b * CH + c) * NTOK + n0 + nl);
    tile[cl][nl + 0] = f2bf(v.x * ga + be);
    tile[cl][nl + 1] = f2bf(v.y * ga + be);
    tile[cl][nl + 2] = f2bf(v.z * ga + be);
    tile[cl][nl + 3] = f2bf(v.w * ga + be);
    __syncthreads();

    const int nw = t >> 3;
    const int cw = (t & 7) * 4;
    short4v o;
    o.x = tile[cw + 0][nw];
    o.y = tile[cw + 1][nw];
    o.z = tile[cw + 2][nw];
    o.w = tile[cw + 3][nw];
    *(short4v*)(hnT + ((size_t)b * NTOK + n0 + nw) * CH + c0 + cw) = o;
}

// ---------------------------------------------------------------------------
// Weight casts. Grid (256, 4).
// ---------------------------------------------------------------------------
__global__ __launch_bounds__(256)
void cast_weights(const float* q, const float* k, const float* v, const float* p,
                  short* wqk, short* wv, short* wp)
{
    const float* w; short* o;
    switch (blockIdx.y) {
        case 0: w = q; o = wqk; break;
        case 1: w = k; o = wqk + CH * CH; break;
        case 2: w = v; o = wv; break;
        default: w = p; o = wp; break;
    }
    const int i = blockIdx.x * 256 + threadIdx.x;
    const float4 vv = ((const float4*)w)[i];
    short4v s; s.x = f2bf(vv.x); s.y = f2bf(vv.y); s.z = f2bf(vv.z); s.w = f2bf(vv.w);
    ((short4v*)o)[i] = s;
}

__global__ __launch_bounds__(256)
void concat_bias(const float* q_b, const float* k_b, float* qkb)
{
    const int i = blockIdx.x * 256 + threadIdx.x;
    qkb[i] = (i < CH) ? q_b[i] : k_b[i - CH];
}

__global__ __launch_bounds__(256)
void zero_f32(float* __restrict__ p)
{
    p[blockIdx.x * 256 + threadIdx.x] = 0.f;
}

// ---------------------------------------------------------------------------
// 256x256 4-phase bf16 GEMM (TN), 512 threads, counted-vmcnt pipeline
// + T2 swizzle + T5 setprio. MODE 2 = bf16 exp(out) + fused row-sum atomics.
// Best-known structure for the short-K (K=512) scores GEMM (round 7: 116us).
// ---------------------------------------------------------------------------
#define BAR8() asm volatile("s_barrier" ::: "memory")
#define WAITV4() asm volatile("s_waitcnt vmcnt(4)" ::: "memory")
#define WAITV0() asm volatile("s_waitcnt vmcnt(0)" ::: "memory")
#define LGKMW() asm volatile("s_waitcnt lgkmcnt(0)" ::: "memory")

#define STAGE_A(bufp, kt, u) do {                                             \
    const int r0_ = arow0 + (u) * 64;                                         \
    load_lds16(Ap + (size_t)(m0 + r0_) * lda + (kt) * 64 + sc * 8,            \
               &lds[(bufp) * NSH + r0_ * 64 + lc * 8]);                       \
    load_lds16(Ap + (size_t)(m0 + r0_ + 128) * lda + (kt) * 64 + sc * 8,      \
               &lds[(bufp) * NSH + (r0_ + 128) * 64 + lc * 8]);               \
} while (0)

#define STAGE_B(bufp, kt, u) do {                                             \
    const int r0_ = brow0 + (u) * 32;                                         \
    load_lds16(Bp + (size_t)(n0 + r0_) * ldb + (kt) * 64 + sc * 8,            \
               &lds[(bufp) * NSH + 16384 + r0_ * 64 + lc * 8]);               \
    load_lds16(Bp + (size_t)(n0 + r0_ + 128) * ldb + (kt) * 64 + sc * 8,      \
               &lds[(bufp) * NSH + 16384 + (r0_ + 128) * 64 + lc * 8]);       \
} while (0)

#define READA(bufp, mh) do {                                                  \
    const short* bp_ = &lds[(bufp) * NSH];                                    \
    _Pragma("unroll")                                                         \
    for (int mt = 0; mt < 4; mt++) {                                          \
        const int row_ = wr * 128 + (mh) * 64 + mt * 16 + lr;                 \
        af[mt][0] = *(const short8*)&bp_[row_ * 64 + ((0 + lq) ^ (lr & 7)) * 8]; \
        af[mt][1] = *(const short8*)&bp_[row_ * 64 + ((4 + lq) ^ (lr & 7)) * 8]; \
    } } while (0)

#define READB(bufp, nh) do {                                                  \
    const short* bp_ = &lds[(bufp) * NSH + 16384];                            \
    _Pragma("unroll")                                                         \
    for (int nt = 0; nt < 2; nt++) {                                          \
        const int row_ = wc * 64 + (nh) * 32 + nt * 16 + lr;                  \
        bfr[(nh) * 2 + nt][0] = *(const short8*)&bp_[row_ * 64 + ((0 + lq) ^ (lr & 7)) * 8]; \
        bfr[(nh) * 2 + nt][1] = *(const short8*)&bp_[row_ * 64 + ((4 + lq) ^ (lr & 7)) * 8]; \
    } } while (0)

#define MMAQ(mh, nh) do {                                                     \
    __builtin_amdgcn_s_setprio(1);                                            \
    _Pragma("unroll")                                                         \
    for (int mt = 0; mt < 4; mt++)                                            \
        _Pragma("unroll")                                                     \
        for (int nt = 0; nt < 2; nt++) {                                      \
            acc[(mh)*4+mt][(nh)*2+nt] = __builtin_amdgcn_mfma_f32_16x16x32_bf16( \
                af[mt][0], bfr[(nh)*2+nt][0], acc[(mh)*4+mt][(nh)*2+nt], 0, 0, 0); \
            acc[(mh)*4+mt][(nh)*2+nt] = __builtin_amdgcn_mfma_f32_16x16x32_bf16( \
                af[mt][1], bfr[(nh)*2+nt][1], acc[(mh)*4+mt][(nh)*2+nt], 0, 0, 0); \
        }                                                                     \
    __builtin_amdgcn_s_setprio(0);                                            \
} while (0)

template<int MODE, int SWAP_XY, int SPLITK>
__global__ __launch_bounds__(512)
void gemm8p(const short* __restrict__ A, const short* __restrict__ B,
            short* __restrict__ Cout, float* __restrict__ rs, float scale,
            int K, int lda, int ldb, int ldc, long sA, long sB, long sC)
{
    constexpr int NSH = 32768;                  // shorts per K-tile buffer
    __shared__ __align__(16) short lds[65536];  // 128 KiB: 2 bufs / epilogue Cs

    const int z = blockIdx.z;
    const int zb = SPLITK ? (z & 3) : z;
    const int koff = SPLITK ? (z >> 2) * K : 0;
    const short* Ap = A + (size_t)zb * sA + koff;
    const short* Bp = B + (size_t)zb * sB + koff;
    const int m0 = (SWAP_XY ? blockIdx.x : blockIdx.y) * 256;
    const int n0 = (SWAP_XY ? blockIdx.y : blockIdx.x) * 256;

    const int t = threadIdx.x;
    const int w = t >> 6, lane = t & 63;
    const int wr = w >> 2, wc = w & 3;
    const int lr = lane & 15, lq = lane >> 4;

    const int l8 = lane >> 3;            // row-in-8
    const int lc = lane & 7;             // linear dest chunk
    const int sc = lc ^ l8;              // swizzled source chunk (T2)
    const int arow0 = w * 8 + l8;                      // A unit0, j=0 rows
    const int brow0 = (w >> 2) * 64 + (w & 3) * 8 + l8; // B unit0, j=0 rows

    short8 af[4][2], bfr[4][2];
    floatx4 acc[8][4];
#pragma unroll
    for (int i = 0; i < 8; i++)
#pragma unroll
        for (int j = 0; j < 4; j++)
            acc[i][j] = (floatx4){0.f, 0.f, 0.f, 0.f};

    const int NKT = K >> 6;
    const int NIT = K >> 7;

    // Prologue: buf0 <- kt0 full (8 loads), buf1 <- kt1 u0 halves (4 loads).
    STAGE_A(0, 0, 0); STAGE_B(0, 0, 0); STAGE_A(0, 0, 1); STAGE_B(0, 0, 1);
    STAGE_A(1, 1, 0); STAGE_B(1, 1, 0);

    for (int it = 0; it < NIT; it++) {
        const int ktb = 2 * it + 1;
        int kt2 = 2 * it + 2; if (kt2 >= NKT) kt2 -= 2;
        int kt3 = 2 * it + 3; if (kt3 >= NKT) kt3 -= 2;
        // P0
        WAITV4(); BAR8();
        READA(0, 0); READB(0, 0); READB(0, 1);
        STAGE_B(1, ktb, 1); STAGE_A(1, ktb, 1);
        BAR8(); LGKMW(); MMAQ(0, 0); MMAQ(0, 1); BAR8();
        // P1
        READA(0, 1);
        STAGE_A(0, kt2, 0); STAGE_B(0, kt2, 0);
        BAR8(); LGKMW(); MMAQ(1, 0); MMAQ(1, 1); BAR8();
        // P2
        WAITV4(); BAR8();
        READA(1, 0); READB(1, 0); READB(1, 1);
        STAGE_A(0, kt2, 1); STAGE_B(0, kt2, 1);
        BAR8(); LGKMW(); MMAQ(0, 0); MMAQ(0, 1); BAR8();
        // P3
        READA(1, 1);
        STAGE_A(1, kt3, 0); STAGE_B(1, kt3, 0);
        BAR8(); LGKMW(); MMAQ(1, 0); MMAQ(1, 1); BAR8();
    }
    WAITV0(); BAR8();      // drain clamped tail stages before LDS reuse

    // Epilogue: stage full 256x256 bf16 C tile in LDS (row-XOR-swizzled cols),
    // then coalesced 512B stores. MODE 2: exp + fused row-sum atomics.
    short* Cs = lds;
    const size_t cz = (size_t)z * sC;
#pragma unroll
    for (int mh = 0; mh < 2; mh++)
#pragma unroll
        for (int mt = 0; mt < 4; mt++)
#pragma unroll
            for (int r = 0; r < 4; r++) {
                const int row = wr * 128 + mh * 64 + mt * 16 + lq * 4 + r;
                float sm = 0.f;
#pragma unroll
                for (int nh = 0; nh < 2; nh++)
#pragma unroll
                    for (int nt = 0; nt < 2; nt++) {
                        const int col = wc * 64 + nh * 32 + nt * 16 + lr;
                        float v = acc[mh * 4 + mt][nh * 2 + nt][r] * scale;
                        if (MODE == 2) { v = __expf(v); sm += v; }
                        Cs[row * 256 + (col ^ ((row & 7) << 4))] = f2bf(v);
                    }
                if (MODE == 2) {
                    sm += __shfl_xor(sm, 1);
                    sm += __shfl_xor(sm, 2);
                    sm += __shfl_xor(sm, 4);
                    sm += __shfl_xor(sm, 8);
                    if (lr == 0)
                        atomicAdd(&rs[(size_t)zb * NTOK + m0 + row], sm);
                }
            }
    __syncthreads();
#pragma unroll
    for (int i2 = 0; i2 < 16; i2++) {
        const int row = w * 32 + i2 * 2 + (lane >> 5);
        const int col = (lane & 31) * 8;
        short8 val = *(const short8*)&Cs[row * 256 + (col ^ ((row & 7) << 4))];
        *(short8*)&Cout[cz + (size_t)(m0 + row) * ldc + n0 + col] = val;
    }
}

// ---------------------------------------------------------------------------
// bf16 MFMA GEMM (TN) 128x128 2-barrier. T2 swizzle (effective at BK=64).
// DIV_RS: epilogue multiplies each output row by 1/rs[row] (PV normalize).
// ---------------------------------------------------------------------------
template<int BM, int BN, int BK, int WAVES_M, int MODE, int BIAS_M,
         int BIAS_N, int ADD_RES, int SWAP_XY, int SPLITK, int RSUM, int DIV_RS>
__global__ __launch_bounds__(256)
void mfma_gemm(const short* __restrict__ A, const short* __restrict__ B,
               void* __restrict__ Cv, const float* __restrict__ bias,
               const float* __restrict__ res, float* __restrict__ rs,
               float scale,
               int K, int lda, int ldb, int ldc,
               long sA, long sB, long sC)
{
    constexpr int WAVES_N = 4 / WAVES_M;
    constexpr int WM = BM / WAVES_M;
    constexpr int WN = BN / WAVES_N;
    constexpr int MT = WM / 16;
    constexpr int NT = WN / 16;
    constexpr int KS = BK / 32;
    constexpr int TPR = BK / 8;
    constexpr int RPI = 256 / TPR;
    constexpr int CPITCH = BN + 8;
    constexpr int STAGE = BM * BK + BN * BK;
    constexpr int EPI = (MODE >= 1) ? 64 * CPITCH : 0;
    constexpr int LDSE = STAGE > EPI ? STAGE : EPI;

    __shared__ __align__(16) short lds[LDSE];
    short* As = lds;
    short* Bs = lds + BM * BK;

    const int z = blockIdx.z;
    const int zb = SPLITK ? (z & 3) : z;
    const int koff = SPLITK ? (z >> 2) * K : 0;
    const short* Ap = A + (size_t)zb * sA + koff;
    const short* Bp = B + (size_t)zb * sB + koff;

    const int m0 = (SWAP_XY ? blockIdx.x : blockIdx.y) * BM;
    const int n0 = (SWAP_XY ? blockIdx.y : blockIdx.x) * BN;
    const int t = threadIdx.x;
    const int w = t >> 6, lane = t & 63;
    const int wm = (w % WAVES_M) * WM;
    const int wn = (w / WAVES_M) * WN;
    const int lr = lane & 15, lq = lane >> 4;

    floatx4 acc[MT][NT];
#pragma unroll
    for (int mt = 0; mt < MT; mt++)
#pragma unroll
        for (int nt = 0; nt < NT; nt++)
            acc[mt][nt] = (floatx4){0.f, 0.f, 0.f, 0.f};

    const int rA = t / TPR;
    const int kA = (t % TPR) * 8;
    const int kAs = ((t % TPR) ^ (rA & (TPR - 1))) * 8;
    const int xorv = (lr & (TPR - 1)) * 8;

    for (int k0 = 0; k0 < K; k0 += BK) {
#pragma unroll
        for (int r = 0; r < BM; r += RPI)
            load_lds16(Ap + (size_t)(m0 + r + rA) * lda + k0 + kAs,
                       &As[(r + rA) * BK + kA]);
#pragma unroll
        for (int r = 0; r < BN; r += RPI)
            load_lds16(Bp + (size_t)(n0 + r + rA) * ldb + k0 + kAs,
                       &Bs[(r + rA) * BK + kA]);
        __syncthreads();

#pragma unroll
        for (int ks = 0; ks < KS; ks++) {
            short8 af[MT], bfr[NT];
#pragma unroll
            for (int mt = 0; mt < MT; mt++)
                af[mt] = *(const short8*)&As[(wm + mt * 16 + lr) * BK + ((ks * 32 + lq * 8) ^ xorv)];
#pragma unroll
            for (int nt = 0; nt < NT; nt++)
                bfr[nt] = *(const short8*)&Bs[(wn + nt * 16 + lr) * BK + ((ks * 32 + lq * 8) ^ xorv)];
#pragma unroll
            for (int mt = 0; mt < MT; mt++)
#pragma unroll
                for (int nt = 0; nt < NT; nt++)
                    acc[mt][nt] = __builtin_amdgcn_mfma_f32_16x16x32_bf16(
                        af[mt], bfr[nt], acc[mt][nt], 0, 0, 0);
        }
        __syncthreads();
    }

    // C/D: col = lane&15, row = (lane>>4)*4 + r  [m89-verified]
    const size_t cz = (size_t)z * sC;
    if (MODE >= 1) {
        short* Cs = lds;
        short* Cout2 = (short*)Cv;
        constexpr int VPR = BN / 8;
#pragma unroll
        for (int c = 0; c < BM / 64; c++) {
            if (wm == c * 64) {
#pragma unroll
                for (int mt = 0; mt < MT; mt++) {
#pragma unroll
                    for (int r = 0; r < 4; r++) {
                        const int rowLoc = wm + mt * 16 + lq * 4 + r;
                        const int rowCs = rowLoc - c * 64;
                        const float bm = BIAS_M ? bias[m0 + rowLoc] : 0.f;
                        const float rdiv = DIV_RS
                            ? 1.f / rs[(size_t)zb * NTOK + m0 + rowLoc] : 1.f;
                        float s = 0.f;
#pragma unroll
                        for (int nt = 0; nt < NT; nt++) {
                            const int colLoc = wn + nt * 16 + lr;
                            float v = acc[mt][nt][r] * scale + bm;
                            if (BIAS_N) v += bias[n0 + colLoc];
                            if (MODE == 2) v = __expf(v);
                            if (DIV_RS) v *= rdiv;
                            if (RSUM) s += v;
                            Cs[rowCs * CPITCH + colLoc] = f2bf(v);
                        }
                        if (RSUM) {
                            s += __shfl_xor(s, 1);
                            s += __shfl_xor(s, 2);
                            s += __shfl_xor(s, 4);
                            s += __shfl_xor(s, 8);
                            if (lr == 0)
                                atomicAdd(&rs[(size_t)zb * NTOK + m0 + rowLoc], s);
                        }
                    }
                }
            }
            __syncthreads();
            constexpr int ITER = 64 * VPR / 256;
#pragma unroll
            for (int i = 0; i < ITER; i++) {
                const int idx = i * 256 + t;
                const int row = idx / VPR;
                const int cv = idx % VPR;
                short8 val = *(const short8*)&Cs[row * CPITCH + cv * 8];
                *(short8*)&Cout2[cz + (size_t)(m0 + c * 64 + row) * ldc + n0 + cv * 8] = val;
            }
            if (c + 1 < BM / 64) __syncthreads();
        }
    } else {
#pragma unroll
        for (int mt = 0; mt < MT; mt++) {
#pragma unroll
            for (int r = 0; r < 4; r++) {
                const int row = m0 + wm + mt * 16 + lq * 4 + r;
                const float bm = BIAS_M ? bias[row] : 0.f;
#pragma unroll
                for (int nt = 0; nt < NT; nt++) {
                    const int col = n0 + wn + nt * 16 + lr;
                    float v = acc[mt][nt][r] * scale + bm;
                    if (BIAS_N) v += bias[col];
                    const size_t idx = cz + (size_t)row * ldc + col;
                    if (ADD_RES) v += res[idx];
                    ((float*)Cv)[idx] = v;
                }
            }
        }
    }
}

// ---------------------------------------------------------------------------
// Launch
// ---------------------------------------------------------------------------
extern "C" void kernel_launch(void* const* d_in, const int* in_sizes, int n_in,
                              void* d_out, int out_size, void* d_ws, size_t ws_size,
                              hipStream_t stream)
{
    (void)in_sizes; (void)n_in; (void)out_size; (void)ws_size;
    const float* x      = (const float*)d_in[0];
    const float* norm_w = (const float*)d_in[1];
    const float* norm_b = (const float*)d_in[2];
    const float* q_w    = (const float*)d_in[3];
    const float* q_b    = (const float*)d_in[4];
    const float* k_w    = (const float*)d_in[5];
    const float* k_b    = (const float*)d_in[6];
    const float* v_w    = (const float*)d_in[7];
    const float* v_b    = (const float*)d_in[8];
    const float* p_w    = (const float*)d_in[9];
    const float* p_b    = (const float*)d_in[10];

    const size_t CN2 = (size_t)NTOK * CH;

    short* hnT = (short*)d_ws;                        // [B][N][C]
    short* QK  = hnT + (size_t)BATCH * CN2;           // [B][N][1024]
    short* V   = QK  + (size_t)BATCH * NTOK * 1024;   // [B][C][N]
    short* O   = V   + (size_t)BATCH * CN2;           // [B][N][C] (normalized)
    short* wqk = O   + (size_t)BATCH * CN2;           // [1024][512]
    short* wv  = wqk + (size_t)1024 * CH;
    short* wp  = wv  + (size_t)CH * CH;
    short* S   = wp  + (size_t)CH * CH;               // E = exp(scores) [B][N][N] bf16
    float* qkb = (float*)(S + (size_t)BATCH * NTOK * NTOK);   // [1024]
    float2* partials = (float2*)(qkb + 1024);                 // [512]
    float* RS = (float*)(partials + 512);                     // [B][N] rowsums

    gn_stats_partial<<<dim3(4, BATCH * NGRP), 256, 0, stream>>>(x, partials);
    cast_weights<<<dim3(256, 4), 256, 0, stream>>>(q_w, k_w, v_w, p_w, wqk, wv, wp);
    concat_bias<<<4, 256, 0, stream>>>(q_b, k_b, qkb);
    zero_f32<<<BATCH * NTOK / 256, 256, 0, stream>>>(RS);
    gn_apply_t<<<dim3(NTOK / 32, CH / 32, BATCH), 256, 0, stream>>>(
        x, norm_w, norm_b, partials, hnT);

    // Fused Q+K conv (128^2, BK=64)
    mfma_gemm<128, 128, 64, 2, 1, 0, 1, 0, 0, 0, 0, 0><<<dim3(1024 / 128, NTOK / 128, BATCH), 256, 0, stream>>>(
        hnT, wqk, QK, qkb, nullptr, nullptr, 1.f, CH, CH, CH, 1024,
        (long)CN2, 0, (long)NTOK * 1024);
    // V conv
    mfma_gemm<128, 128, 64, 2, 1, 1, 0, 0, 0, 0, 0, 0><<<dim3(NTOK / 128, CH / 128, BATCH), 256, 0, stream>>>(
        wv, hnT, V, v_b, nullptr, nullptr, 1.f, CH, CH, CH, NTOK,
        0, (long)CN2, (long)CN2);

    const float scale = 1.0f / sqrtf((float)CH);
    // scores -> E = exp(s*scale) bf16 + fused row sums (4-phase 256^2, r7 best)
    gemm8p<2, 0, 0><<<dim3(NTOK / 256, NTOK / 256, BATCH), 512, 0, stream>>>(
        QK, QK + CH, S, RS, scale, CH, 1024, 1024, NTOK,
        (long)NTOK * 1024, (long)NTOK * 1024, (long)NTOK * NTOK);
    // PV: no split-K. 128^2 BK=64, full K=4096 (NIT=64, deep amortization),
    // 512 blocks (~4-5/CU co-resident pairs), epilogue applies 1/RS -> O.
    mfma_gemm<128, 128, 64, 2, 1, 0, 0, 0, 1, 0, 0, 1><<<dim3(NTOK / 128, CH / 128, BATCH), 256, 0, stream>>>(
        S, V, O, nullptr, nullptr, RS, 1.f, NTOK, NTOK, NTOK, CH,
        (long)NTOK * NTOK, (long)CN2, (long)CN2);

    // proj + bias + residual -> out fp32 [b][c][n]
    mfma_gemm<128, 128, 64, 2, 0, 1, 0, 1, 0, 0, 0, 0><<<dim3(NTOK / 128, CH / 128, BATCH), 256, 0, stream>>>(
        wp, O, d_out, p_b, x, nullptr, 1.f, CH, CH, CH, NTOK,
        0, (long)CN2, (long)CN2);
}

// Round 10
// 352.689 us; speedup vs baseline: 1.2512x; 1.0577x over previous
//
#include <hip/hip_runtime.h>
#include <math.h>

#define BATCH 4
#define CH 512
#define NTOK 4096
#define NGRP 32
#define CPG 16
#define GN_EPS 1e-6f

typedef __attribute__((ext_vector_type(8))) short short8;
typedef __attribute__((ext_vector_type(4))) short short4v;
typedef __attribute__((ext_vector_type(4))) float floatx4;

__device__ __forceinline__ short f2bf(float f) {
    unsigned u = __float_as_uint(f);
    u += 0x7fffu + ((u >> 16) & 1u);
    return (short)(u >> 16);
}
__device__ __forceinline__ float bf2f(short s) {
    return __uint_as_float(((unsigned)(unsigned short)s) << 16);
}

__device__ __forceinline__ void load_lds16(const void* g, void* l) {
    __builtin_amdgcn_global_load_lds(
        (const __attribute__((address_space(1))) void*)g,
        (__attribute__((address_space(3))) void*)l,
        16, 0, 0);
}

// ---------------------------------------------------------------------------
// GroupNorm stats, partial: grid (4 parts, 128 bg). partials[bg*4+p]=(sum,ssq)
// ---------------------------------------------------------------------------
__global__ __launch_bounds__(256)
void gn_stats_partial(const float* __restrict__ x, float2* __restrict__ partials)
{
    const int part = blockIdx.x;
    const int bg = blockIdx.y;
    const float4* xp = (const float4*)(x + (size_t)bg * CPG * NTOK) + part * 4096;
    float s = 0.f, ss = 0.f;
    for (int i = threadIdx.x; i < 4096; i += 256) {
        float4 v = xp[i];
        s  += v.x + v.y + v.z + v.w;
        ss += v.x * v.x + v.y * v.y + v.z * v.z + v.w * v.w;
    }
    __shared__ float r0[4], r1[4];
    for (int off = 32; off >= 1; off >>= 1) {
        s  += __shfl_down(s, off);
        ss += __shfl_down(ss, off);
    }
    const int lane = threadIdx.x & 63, wave = threadIdx.x >> 6;
    if (lane == 0) { r0[wave] = s; r1[wave] = ss; }
    __syncthreads();
    if (threadIdx.x == 0) {
        float2 o;
        o.x = r0[0] + r0[1] + r0[2] + r0[3];
        o.y = r1[0] + r1[1] + r1[2] + r1[3];
        partials[bg * 4 + part] = o;
    }
}

// ---------------------------------------------------------------------------
// GroupNorm apply + transpose + bf16. x[b][c][n] -> hnT[b][n][c] bf16.
// ---------------------------------------------------------------------------
__global__ __launch_bounds__(256)
void gn_apply_t(const float* __restrict__ x, const float* __restrict__ gamma,
                const float* __restrict__ beta, const float2* __restrict__ partials,
                short* __restrict__ hnT)
{
    const int b = blockIdx.z;
    const int c0 = blockIdx.y * 32;
    const int n0 = blockIdx.x * 32;
    __shared__ short tile[32][33];
    const int t = threadIdx.x;

    const int cl = t >> 3;
    const int nl = (t & 7) * 4;
    const int c = c0 + cl;
    const int bg = b * NGRP + c / CPG;
    float2 p0 = partials[bg * 4 + 0], p1 = partials[bg * 4 + 1];
    float2 p2 = partials[bg * 4 + 2], p3 = partials[bg * 4 + 3];
    const float inv = 1.f / (float)(CPG * NTOK);
    const float mean = (p0.x + p1.x + p2.x + p3.x) * inv;
    const float var = (p0.y + p1.y + p2.y + p3.y) * inv - mean * mean;
    const float rstd = rsqrtf(var + GN_EPS);
    const float ga = gamma[c] * rstd, be = beta[c] - mean * ga;
    const float4 v = *(const float4*)(x + ((size_t)b * CH + c) * NTOK + n0 + nl);
    tile[cl][nl + 0] = f2bf(v.x * ga + be);
    tile[cl][nl + 1] = f2bf(v.y * ga + be);
    tile[cl][nl + 2] = f2bf(v.z * ga + be);
    tile[cl][nl + 3] = f2bf(v.w * ga + be);
    __syncthreads();

    const int nw = t >> 3;
    const int cw = (t & 7) * 4;
    short4v o;
    o.x = tile[cw + 0][nw];
    o.y = tile[cw + 1][nw];
    o.z = tile[cw + 2][nw];
    o.w = tile[cw + 3][nw];
    *(short4v*)(hnT + ((size_t)b * NTOK + n0 + nw) * CH + c0 + cw) = o;
}

// ---------------------------------------------------------------------------
// Weight casts. Grid (256, 4).
// ---------------------------------------------------------------------------
__global__ __launch_bounds__(256)
void cast_weights(const float* q, const float* k, const float* v, const float* p,
                  short* wqk, short* wv, short* wp)
{
    const float* w; short* o;
    switch (blockIdx.y) {
        case 0: w = q; o = wqk; break;
        case 1: w = k; o = wqk + CH * CH; break;
        case 2: w = v; o = wv; break;
        default: w = p; o = wp; break;
    }
    const int i = blockIdx.x * 256 + threadIdx.x;
    const float4 vv = ((const float4*)w)[i];
    short4v s; s.x = f2bf(vv.x); s.y = f2bf(vv.y); s.z = f2bf(vv.z); s.w = f2bf(vv.w);
    ((short4v*)o)[i] = s;
}

__global__ __launch_bounds__(256)
void concat_bias(const float* q_b, const float* k_b, float* qkb)
{
    const int i = blockIdx.x * 256 + threadIdx.x;
    qkb[i] = (i < CH) ? q_b[i] : k_b[i - CH];
}

__global__ __launch_bounds__(256)
void zero_f32(float* __restrict__ p)
{
    p[blockIdx.x * 256 + threadIdx.x] = 0.f;
}

// ---------------------------------------------------------------------------
// 256x256 4-phase bf16 GEMM (TN), 512 threads, counted-vmcnt pipeline
// + T2 swizzle + T5 setprio. MODE 2 = bf16 exp(out) + fused row-sum atomics.
// Best-known structure for the short-K scores GEMM (r7: 116us) and the
// split-K PV (r7). UNCHANGED from round 7.
// ---------------------------------------------------------------------------
#define BAR8() asm volatile("s_barrier" ::: "memory")
#define WAITV4() asm volatile("s_waitcnt vmcnt(4)" ::: "memory")
#define WAITV0() asm volatile("s_waitcnt vmcnt(0)" ::: "memory")
#define LGKMW() asm volatile("s_waitcnt lgkmcnt(0)" ::: "memory")

#define STAGE_A(bufp, kt, u) do {                                             \
    const int r0_ = arow0 + (u) * 64;                                         \
    load_lds16(Ap + (size_t)(m0 + r0_) * lda + (kt) * 64 + sc * 8,            \
               &lds[(bufp) * NSH + r0_ * 64 + lc * 8]);                       \
    load_lds16(Ap + (size_t)(m0 + r0_ + 128) * lda + (kt) * 64 + sc * 8,      \
               &lds[(bufp) * NSH + (r0_ + 128) * 64 + lc * 8]);               \
} while (0)

#define STAGE_B(bufp, kt, u) do {                                             \
    const int r0_ = brow0 + (u) * 32;                                         \
    load_lds16(Bp + (size_t)(n0 + r0_) * ldb + (kt) * 64 + sc * 8,            \
               &lds[(bufp) * NSH + 16384 + r0_ * 64 + lc * 8]);               \
    load_lds16(Bp + (size_t)(n0 + r0_ + 128) * ldb + (kt) * 64 + sc * 8,      \
               &lds[(bufp) * NSH + 16384 + (r0_ + 128) * 64 + lc * 8]);       \
} while (0)

#define READA(bufp, mh) do {                                                  \
    const short* bp_ = &lds[(bufp) * NSH];                                    \
    _Pragma("unroll")                                                         \
    for (int mt = 0; mt < 4; mt++) {                                          \
        const int row_ = wr * 128 + (mh) * 64 + mt * 16 + lr;                 \
        af[mt][0] = *(const short8*)&bp_[row_ * 64 + ((0 + lq) ^ (lr & 7)) * 8]; \
        af[mt][1] = *(const short8*)&bp_[row_ * 64 + ((4 + lq) ^ (lr & 7)) * 8]; \
    } } while (0)

#define READB(bufp, nh) do {                                                  \
    const short* bp_ = &lds[(bufp) * NSH + 16384];                            \
    _Pragma("unroll")                                                         \
    for (int nt = 0; nt < 2; nt++) {                                          \
        const int row_ = wc * 64 + (nh) * 32 + nt * 16 + lr;                  \
        bfr[(nh) * 2 + nt][0] = *(const short8*)&bp_[row_ * 64 + ((0 + lq) ^ (lr & 7)) * 8]; \
        bfr[(nh) * 2 + nt][1] = *(const short8*)&bp_[row_ * 64 + ((4 + lq) ^ (lr & 7)) * 8]; \
    } } while (0)

#define MMAQ(mh, nh) do {                                                     \
    __builtin_amdgcn_s_setprio(1);                                            \
    _Pragma("unroll")                                                         \
    for (int mt = 0; mt < 4; mt++)                                            \
        _Pragma("unroll")                                                     \
        for (int nt = 0; nt < 2; nt++) {                                      \
            acc[(mh)*4+mt][(nh)*2+nt] = __builtin_amdgcn_mfma_f32_16x16x32_bf16( \
                af[mt][0], bfr[(nh)*2+nt][0], acc[(mh)*4+mt][(nh)*2+nt], 0, 0, 0); \
            acc[(mh)*4+mt][(nh)*2+nt] = __builtin_amdgcn_mfma_f32_16x16x32_bf16( \
                af[mt][1], bfr[(nh)*2+nt][1], acc[(mh)*4+mt][(nh)*2+nt], 0, 0, 0); \
        }                                                                     \
    __builtin_amdgcn_s_setprio(0);                                            \
} while (0)

template<int MODE, int SWAP_XY, int SPLITK>
__global__ __launch_bounds__(512)
void gemm8p(const short* __restrict__ A, const short* __restrict__ B,
            short* __restrict__ Cout, float* __restrict__ rs, float scale,
            int K, int lda, int ldb, int ldc, long sA, long sB, long sC)
{
    constexpr int NSH = 32768;                  // shorts per K-tile buffer
    __shared__ __align__(16) short lds[65536];  // 128 KiB: 2 bufs / epilogue Cs

    const int z = blockIdx.z;
    const int zb = SPLITK ? (z & 3) : z;
    const int koff = SPLITK ? (z >> 2) * K : 0;
    const short* Ap = A + (size_t)zb * sA + koff;
    const short* Bp = B + (size_t)zb * sB + koff;
    const int m0 = (SWAP_XY ? blockIdx.x : blockIdx.y) * 256;
    const int n0 = (SWAP_XY ? blockIdx.y : blockIdx.x) * 256;

    const int t = threadIdx.x;
    const int w = t >> 6, lane = t & 63;
    const int wr = w >> 2, wc = w & 3;
    const int lr = lane & 15, lq = lane >> 4;

    const int l8 = lane >> 3;            // row-in-8
    const int lc = lane & 7;             // linear dest chunk
    const int sc = lc ^ l8;              // swizzled source chunk (T2)
    const int arow0 = w * 8 + l8;                      // A unit0, j=0 rows
    const int brow0 = (w >> 2) * 64 + (w & 3) * 8 + l8; // B unit0, j=0 rows

    short8 af[4][2], bfr[4][2];
    floatx4 acc[8][4];
#pragma unroll
    for (int i = 0; i < 8; i++)
#pragma unroll
        for (int j = 0; j < 4; j++)
            acc[i][j] = (floatx4){0.f, 0.f, 0.f, 0.f};

    const int NKT = K >> 6;
    const int NIT = K >> 7;

    // Prologue: buf0 <- kt0 full (8 loads), buf1 <- kt1 u0 halves (4 loads).
    STAGE_A(0, 0, 0); STAGE_B(0, 0, 0); STAGE_A(0, 0, 1); STAGE_B(0, 0, 1);
    STAGE_A(1, 1, 0); STAGE_B(1, 1, 0);

    for (int it = 0; it < NIT; it++) {
        const int ktb = 2 * it + 1;
        int kt2 = 2 * it + 2; if (kt2 >= NKT) kt2 -= 2;
        int kt3 = 2 * it + 3; if (kt3 >= NKT) kt3 -= 2;
        // P0
        WAITV4(); BAR8();
        READA(0, 0); READB(0, 0); READB(0, 1);
        STAGE_B(1, ktb, 1); STAGE_A(1, ktb, 1);
        BAR8(); LGKMW(); MMAQ(0, 0); MMAQ(0, 1); BAR8();
        // P1
        READA(0, 1);
        STAGE_A(0, kt2, 0); STAGE_B(0, kt2, 0);
        BAR8(); LGKMW(); MMAQ(1, 0); MMAQ(1, 1); BAR8();
        // P2
        WAITV4(); BAR8();
        READA(1, 0); READB(1, 0); READB(1, 1);
        STAGE_A(0, kt2, 1); STAGE_B(0, kt2, 1);
        BAR8(); LGKMW(); MMAQ(0, 0); MMAQ(0, 1); BAR8();
        // P3
        READA(1, 1);
        STAGE_A(1, kt3, 0); STAGE_B(1, kt3, 0);
        BAR8(); LGKMW(); MMAQ(1, 0); MMAQ(1, 1); BAR8();
    }
    WAITV0(); BAR8();      // drain clamped tail stages before LDS reuse

    // Epilogue: stage full 256x256 bf16 C tile in LDS (row-XOR-swizzled cols),
    // then coalesced 512B stores. MODE 2: exp + fused row-sum atomics.
    short* Cs = lds;
    const size_t cz = (size_t)z * sC;
#pragma unroll
    for (int mh = 0; mh < 2; mh++)
#pragma unroll
        for (int mt = 0; mt < 4; mt++)
#pragma unroll
            for (int r = 0; r < 4; r++) {
                const int row = wr * 128 + mh * 64 + mt * 16 + lq * 4 + r;
                float sm = 0.f;
#pragma unroll
                for (int nh = 0; nh < 2; nh++)
#pragma unroll
                    for (int nt = 0; nt < 2; nt++) {
                        const int col = wc * 64 + nh * 32 + nt * 16 + lr;
                        float v = acc[mh * 4 + mt][nh * 2 + nt][r] * scale;
                        if (MODE == 2) { v = __expf(v); sm += v; }
                        Cs[row * 256 + (col ^ ((row & 7) << 4))] = f2bf(v);
                    }
                if (MODE == 2) {
                    sm += __shfl_xor(sm, 1);
                    sm += __shfl_xor(sm, 2);
                    sm += __shfl_xor(sm, 4);
                    sm += __shfl_xor(sm, 8);
                    if (lr == 0)
                        atomicAdd(&rs[(size_t)zb * NTOK + m0 + row], sm);
                }
            }
    __syncthreads();
#pragma unroll
    for (int i2 = 0; i2 < 16; i2++) {
        const int row = w * 32 + i2 * 2 + (lane >> 5);
        const int col = (lane & 31) * 8;
        short8 val = *(const short8*)&Cs[row * 256 + (col ^ ((row & 7) << 4))];
        *(short8*)&Cout[cz + (size_t)(m0 + row) * ldc + n0 + col] = val;
    }
}

// ---------------------------------------------------------------------------
// bf16 MFMA GEMM (TN) 128x128 2-barrier. T2 swizzle.
// B_COMBINE: B operand is (B + B2)/rs[row] computed in reg-staging (folds the
// former pv_reduce kernel into proj's B-stage; same LDS slots/swizzle).
// ---------------------------------------------------------------------------
template<int BM, int BN, int BK, int WAVES_M, int MODE, int BIAS_M,
         int BIAS_N, int ADD_RES, int SWAP_XY, int SPLITK, int RSUM,
         int B_COMBINE>
__global__ __launch_bounds__(256)
void mfma_gemm(const short* __restrict__ A, const short* __restrict__ B,
               const short* __restrict__ B2, void* __restrict__ Cv,
               const float* __restrict__ bias, const float* __restrict__ res,
               float* __restrict__ rs, float scale,
               int K, int lda, int ldb, int ldc,
               long sA, long sB, long sC)
{
    constexpr int WAVES_N = 4 / WAVES_M;
    constexpr int WM = BM / WAVES_M;
    constexpr int WN = BN / WAVES_N;
    constexpr int MT = WM / 16;
    constexpr int NT = WN / 16;
    constexpr int KS = BK / 32;
    constexpr int TPR = BK / 8;
    constexpr int RPI = 256 / TPR;
    constexpr int CPITCH = BN + 8;
    constexpr int STAGE = BM * BK + BN * BK;
    constexpr int EPI = (MODE >= 1) ? 64 * CPITCH : 0;
    constexpr int LDSE = STAGE > EPI ? STAGE : EPI;

    __shared__ __align__(16) short lds[LDSE];
    short* As = lds;
    short* Bs = lds + BM * BK;

    const int z = blockIdx.z;
    const int zb = SPLITK ? (z & 3) : z;
    const int koff = SPLITK ? (z >> 2) * K : 0;
    const short* Ap = A + (size_t)zb * sA + koff;
    const short* Bp = B + (size_t)zb * sB + koff;
    const short* Bp2 = B_COMBINE ? (B2 + (size_t)zb * sB + koff) : nullptr;

    const int m0 = (SWAP_XY ? blockIdx.x : blockIdx.y) * BM;
    const int n0 = (SWAP_XY ? blockIdx.y : blockIdx.x) * BN;
    const int t = threadIdx.x;
    const int w = t >> 6, lane = t & 63;
    const int wm = (w % WAVES_M) * WM;
    const int wn = (w / WAVES_M) * WN;
    const int lr = lane & 15, lq = lane >> 4;

    floatx4 acc[MT][NT];
#pragma unroll
    for (int mt = 0; mt < MT; mt++)
#pragma unroll
        for (int nt = 0; nt < NT; nt++)
            acc[mt][nt] = (floatx4){0.f, 0.f, 0.f, 0.f};

    const int rA = t / TPR;
    const int kA = (t % TPR) * 8;
    const int kAs = ((t % TPR) ^ (rA & (TPR - 1))) * 8;
    const int xorv = (lr & (TPR - 1)) * 8;

    // Hoisted per-row 1/rs for B_COMBINE (rows fixed across k).
    float binv[B_COMBINE ? BN / RPI : 1];
    if (B_COMBINE) {
#pragma unroll
        for (int r = 0; r < BN / RPI; r++)
            binv[r] = 1.f / rs[(size_t)zb * NTOK + n0 + r * RPI + rA];
    }

    for (int k0 = 0; k0 < K; k0 += BK) {
#pragma unroll
        for (int r = 0; r < BM; r += RPI)
            load_lds16(Ap + (size_t)(m0 + r + rA) * lda + k0 + kAs,
                       &As[(r + rA) * BK + kA]);
        if (B_COMBINE) {
#pragma unroll
            for (int r = 0; r < BN; r += RPI) {
                const size_t off = (size_t)(n0 + r + rA) * ldb + k0 + kAs;
                short8 a8 = *(const short8*)&Bp[off];
                short8 b8 = *(const short8*)&Bp2[off];
                short8 o8;
#pragma unroll
                for (int e = 0; e < 8; e++)
                    o8[e] = f2bf((bf2f(a8[e]) + bf2f(b8[e])) * binv[r / RPI]);
                *(short8*)&Bs[(r + rA) * BK + kA] = o8;
            }
        } else {
#pragma unroll
            for (int r = 0; r < BN; r += RPI)
                load_lds16(Bp + (size_t)(n0 + r + rA) * ldb + k0 + kAs,
                           &Bs[(r + rA) * BK + kA]);
        }
        __syncthreads();

#pragma unroll
        for (int ks = 0; ks < KS; ks++) {
            short8 af[MT], bfr[NT];
#pragma unroll
            for (int mt = 0; mt < MT; mt++)
                af[mt] = *(const short8*)&As[(wm + mt * 16 + lr) * BK + ((ks * 32 + lq * 8) ^ xorv)];
#pragma unroll
            for (int nt = 0; nt < NT; nt++)
                bfr[nt] = *(const short8*)&Bs[(wn + nt * 16 + lr) * BK + ((ks * 32 + lq * 8) ^ xorv)];
#pragma unroll
            for (int mt = 0; mt < MT; mt++)
#pragma unroll
                for (int nt = 0; nt < NT; nt++)
                    acc[mt][nt] = __builtin_amdgcn_mfma_f32_16x16x32_bf16(
                        af[mt], bfr[nt], acc[mt][nt], 0, 0, 0);
        }
        __syncthreads();
    }

    // C/D: col = lane&15, row = (lane>>4)*4 + r  [m89-verified]
    const size_t cz = (size_t)z * sC;
    if (MODE >= 1) {
        short* Cs = lds;
        short* Cout2 = (short*)Cv;
        constexpr int VPR = BN / 8;
#pragma unroll
        for (int c = 0; c < BM / 64; c++) {
            if (wm == c * 64) {
#pragma unroll
                for (int mt = 0; mt < MT; mt++) {
#pragma unroll
                    for (int r = 0; r < 4; r++) {
                        const int rowLoc = wm + mt * 16 + lq * 4 + r;
                        const int rowCs = rowLoc - c * 64;
                        const float bm = BIAS_M ? bias[m0 + rowLoc] : 0.f;
                        float s = 0.f;
#pragma unroll
                        for (int nt = 0; nt < NT; nt++) {
                            const int colLoc = wn + nt * 16 + lr;
                            float v = acc[mt][nt][r] * scale + bm;
                            if (BIAS_N) v += bias[n0 + colLoc];
                            if (MODE == 2) v = __expf(v);
                            if (RSUM) s += v;
                            Cs[rowCs * CPITCH + colLoc] = f2bf(v);
                        }
                        if (RSUM) {
                            s += __shfl_xor(s, 1);
                            s += __shfl_xor(s, 2);
                            s += __shfl_xor(s, 4);
                            s += __shfl_xor(s, 8);
                            if (lr == 0)
                                atomicAdd(&rs[(size_t)zb * NTOK + m0 + rowLoc], s);
                        }
                    }
                }
            }
            __syncthreads();
            constexpr int ITER = 64 * VPR / 256;
#pragma unroll
            for (int i = 0; i < ITER; i++) {
                const int idx = i * 256 + t;
                const int row = idx / VPR;
                const int cv = idx % VPR;
                short8 val = *(const short8*)&Cs[row * CPITCH + cv * 8];
                *(short8*)&Cout2[cz + (size_t)(m0 + c * 64 + row) * ldc + n0 + cv * 8] = val;
            }
            if (c + 1 < BM / 64) __syncthreads();
        }
    } else {
#pragma unroll
        for (int mt = 0; mt < MT; mt++) {
#pragma unroll
            for (int r = 0; r < 4; r++) {
                const int row = m0 + wm + mt * 16 + lq * 4 + r;
                const float bm = BIAS_M ? bias[row] : 0.f;
#pragma unroll
                for (int nt = 0; nt < NT; nt++) {
                    const int col = n0 + wn + nt * 16 + lr;
                    float v = acc[mt][nt][r] * scale + bm;
                    if (BIAS_N) v += bias[col];
                    const size_t idx = cz + (size_t)row * ldc + col;
                    if (ADD_RES) v += res[idx];
                    ((float*)Cv)[idx] = v;
                }
            }
        }
    }
}

// ---------------------------------------------------------------------------
// Launch
// ---------------------------------------------------------------------------
extern "C" void kernel_launch(void* const* d_in, const int* in_sizes, int n_in,
                              void* d_out, int out_size, void* d_ws, size_t ws_size,
                              hipStream_t stream)
{
    (void)in_sizes; (void)n_in; (void)out_size; (void)ws_size;
    const float* x      = (const float*)d_in[0];
    const float* norm_w = (const float*)d_in[1];
    const float* norm_b = (const float*)d_in[2];
    const float* q_w    = (const float*)d_in[3];
    const float* q_b    = (const float*)d_in[4];
    const float* k_w    = (const float*)d_in[5];
    const float* k_b    = (const float*)d_in[6];
    const float* v_w    = (const float*)d_in[7];
    const float* v_b    = (const float*)d_in[8];
    const float* p_w    = (const float*)d_in[9];
    const float* p_b    = (const float*)d_in[10];

    const size_t CN2 = (size_t)NTOK * CH;

    short* hnT = (short*)d_ws;                        // [B][N][C]
    short* QK  = hnT + (size_t)BATCH * CN2;           // [B][N][1024]; later PV partials [2][B][N][C]
    short* V   = QK  + (size_t)BATCH * NTOK * 1024;   // [B][C][N]
    short* O   = V   + (size_t)BATCH * CN2;           // (unused this round)
    short* wqk = O   + (size_t)BATCH * CN2;           // [1024][512]
    short* wv  = wqk + (size_t)1024 * CH;
    short* wp  = wv  + (size_t)CH * CH;
    short* S   = wp  + (size_t)CH * CH;               // E = exp(scores) [B][N][N] bf16
    float* qkb = (float*)(S + (size_t)BATCH * NTOK * NTOK);   // [1024]
    float2* partials = (float2*)(qkb + 1024);                 // [512]
    float* RS = (float*)(partials + 512);                     // [B][N] rowsums

    gn_stats_partial<<<dim3(4, BATCH * NGRP), 256, 0, stream>>>(x, partials);
    cast_weights<<<dim3(256, 4), 256, 0, stream>>>(q_w, k_w, v_w, p_w, wqk, wv, wp);
    concat_bias<<<4, 256, 0, stream>>>(q_b, k_b, qkb);
    zero_f32<<<BATCH * NTOK / 256, 256, 0, stream>>>(RS);
    gn_apply_t<<<dim3(NTOK / 32, CH / 32, BATCH), 256, 0, stream>>>(
        x, norm_w, norm_b, partials, hnT);

    // Fused Q+K conv (128^2, BK=64)
    mfma_gemm<128, 128, 64, 2, 1, 0, 1, 0, 0, 0, 0, 0><<<dim3(1024 / 128, NTOK / 128, BATCH), 256, 0, stream>>>(
        hnT, wqk, nullptr, QK, qkb, nullptr, nullptr, 1.f, CH, CH, CH, 1024,
        (long)CN2, 0, (long)NTOK * 1024);
    // V conv
    mfma_gemm<128, 128, 64, 2, 1, 1, 0, 0, 0, 0, 0, 0><<<dim3(NTOK / 128, CH / 128, BATCH), 256, 0, stream>>>(
        wv, hnT, nullptr, V, v_b, nullptr, nullptr, 1.f, CH, CH, CH, NTOK,
        0, (long)CN2, (long)CN2);

    const float scale = 1.0f / sqrtf((float)CH);
    // scores -> E = exp(s*scale) bf16 + fused row sums (4-phase 256^2, r7 best)
    gemm8p<2, 0, 0><<<dim3(NTOK / 256, NTOK / 256, BATCH), 512, 0, stream>>>(
        QK, QK + CH, S, RS, scale, CH, 1024, 1024, NTOK,
        (long)NTOK * 1024, (long)NTOK * 1024, (long)NTOK * NTOK);
    // PV split-K=2 (4-phase 256^2, r7), bf16 partials over QK buffer:
    // P[z] at z*CN2, z = split*4+batch.
    gemm8p<1, 1, 1><<<dim3(NTOK / 256, CH / 256, 8), 512, 0, stream>>>(
        S, V, QK, nullptr, 1.f, NTOK / 2, NTOK, NTOK, CH,
        (long)NTOK * NTOK, (long)CN2, (long)CN2);

    // proj + bias + residual -> out fp32 [b][c][n].
    // B operand built in-staging: (P0 + P1) / RS  (pv_reduce folded in).
    mfma_gemm<128, 128, 64, 2, 0, 1, 0, 1, 0, 0, 0, 1><<<dim3(NTOK / 128, CH / 128, BATCH), 256, 0, stream>>>(
        wp, QK, QK + (size_t)BATCH * CN2, d_out, p_b, x, RS, 1.f,
        CH, CH, CH, NTOK, 0, (long)CN2, (long)CN2);
}